// Round 6
// baseline (252.007 us; speedup 1.0000x reference)
//
#include <hip/hip_runtime.h>

// irreps: 512x0e + 256x1o + 128x2e ; x,out: [16384, 1920] fp32, weight: 344064 fp32
// Strategy v7: canonical double-buffered LDS GEMM per segment (m97 structure).
// Each segment = GEMM: C[16384*D, MUL] = A[16384*D, MUL] * W[MUL, MUL].
// Per wg (512 thr, 8 waves): M-tile 64/96/160 logical rows x BN cols, BK=32.
//  - B staged via __builtin_amdgcn_global_load_lds (async DMA, linear copy) from
//    weights pre-packed in [kstep][nsub][lane][8] fragment order -> ds_read_b128
//    at lane*16B is conflict-free. No register prefetch, no asm load hazards.
//  - A staged fp32->bf16 (deinterleaved) into K-contig LDS each step.
//  - One __syncthreads per K-step (write nxt while reading cur).

typedef float  f32x4  __attribute__((ext_vector_type(4)));
typedef short  bf16x8 __attribute__((ext_vector_type(8)));

#define ROWLEN 1920

__device__ __forceinline__ unsigned short f2bf(float f) {
    union { float f; unsigned int u; } c; c.f = f;
    unsigned int u = c.u;
    u += 0x7fffu + ((u >> 16) & 1u);   // round-to-nearest-even
    return (unsigned short)(u >> 16);
}

__device__ __forceinline__ void gload_lds16(const unsigned short* g, unsigned short* l) {
    __builtin_amdgcn_global_load_lds(
        (const __attribute__((address_space(1))) unsigned int*)g,
        (__attribute__((address_space(3))) unsigned int*)l, 16, 0, 0);
}

// Pack W[u][v] (fp32, segments consecutive) into bf16 fragment order:
// wt[base + ((ks*NSUB + nsub)*64 + lane)*8 + j] = W[ks*32 + (lane>>4)*8 + j][nsub*16 + (lane&15)]
__global__ __launch_bounds__(256) void prep_weights(const float* __restrict__ w,
                                                    unsigned short* __restrict__ wt) {
    const int g = blockIdx.x * 256 + threadIdx.x;
    if (g >= 344064) return;
    int base, lmul;
    if      (g < 262144) { base = 0;      lmul = 9; }   // mul=512
    else if (g < 327680) { base = 262144; lmul = 8; }   // mul=256
    else                 { base = 327680; lmul = 7; }   // mul=128
    const int local = g - base;
    const int u = local >> lmul;               // input channel (K)
    const int v = local & ((1 << lmul) - 1);   // output channel (N)
    const int NSUB = 1 << (lmul - 4);          // MUL/16
    const int ks   = u >> 5;
    const int nsub = v >> 4;
    const int lane = (((u >> 3) & 3) << 4) | (v & 15);
    const int j    = u & 7;
    wt[base + ((ks * NSUB + nsub) * 64 + lane) * 8 + j] = f2bf(w[g]);
}

// Logical GEMM rows: lrow = i*TN + nl ; A[lrow][u] = x[n0+nl][X_OFF + u*D + i]
template<int MUL, int D, int TN, int BN, int X_OFF, int WT_BASE, int WROWS>
__device__ __forceinline__ void seg_body(const int wid,
                                         const float* __restrict__ x,
                                         const unsigned short* __restrict__ wt,
                                         float* __restrict__ out,
                                         const float scale,
                                         unsigned short* lds) {
    constexpr int NSTEP    = MUL / 32;
    constexpr int M_LOG    = TN * D;
    constexpr int WCOLS    = 8 / WROWS;
    constexpr int MT       = M_LOG / (16 * WROWS);
    constexpr int NT       = BN / (16 * WCOLS);
    constexpr int NSUB_WG  = BN / 16;
    constexpr int NSUB_SEG = MUL / 16;
    constexpr int NB       = MUL / BN;           // n-blocks per segment (1 or 2)
    constexpr int ST       = 40;                 // A stride shorts (80B: ~2-way banks)
    constexpr int A_BUF    = M_LOG * ST;         // shorts per A buffer
    constexpr int B_BUF    = NSUB_WG * 512;      // shorts per B buffer
    constexpr int F4S      = TN * 8 * D;         // f32x4 per A step
    constexpr int SWEEPS   = (F4S + 511) / 512;
    constexpr int BCALLS   = NSUB_WG / 8;        // gload_lds calls per wave per step

    const int tid    = threadIdx.x;
    const int wave   = tid >> 6;
    const int lane   = tid & 63;
    const int q      = lane >> 4;
    const int t16    = lane & 15;
    const int wg_m   = wid / NB;
    const int nb     = wid - wg_m * NB;
    const int n0     = wg_m * TN;
    const int wave_r = wave / WCOLS;
    const int wave_c = wave - wave_r * WCOLS;

    const float* __restrict__ xbase = x + X_OFF + n0 * ROWLEN;
    unsigned short* __restrict__ Alds = lds;
    unsigned short* __restrict__ Blds = lds + 2 * A_BUF;

    auto stage_B = [&](int buf, int ks) {
        const unsigned short* __restrict__ slab =
            wt + WT_BASE + (ks * NSUB_SEG + nb * NSUB_WG) * 512;
        unsigned short* __restrict__ Bl = Blds + buf * B_BUF;
#pragma unroll
        for (int c = 0; c < BCALLS; ++c) {
            const int blk = wave * BCALLS + c;               // 1KB block index
            gload_lds16(slab + blk * 512 + lane * 8, Bl + blk * 512);
        }
    };

    auto stage_A = [&](int buf, int ks) {
        unsigned short* __restrict__ Al = Alds + buf * A_BUF;
        const float* __restrict__ src = xbase + ks * 32 * D;
#pragma unroll
        for (int s = 0; s < SWEEPS; ++s) {
            const int fi = s * 512 + tid;
            if ((F4S % 512 == 0) || (fi < F4S)) {
                const int nl = fi / (8 * D);                 // const divisor
                const int c4 = (fi - nl * (8 * D)) * 4;
                const f32x4 vv = *(const f32x4*)(src + nl * ROWLEN + c4);
                if (D == 1) {
                    unsigned int lo = (unsigned int)f2bf(vv[0]) | ((unsigned int)f2bf(vv[1]) << 16);
                    unsigned int hi = (unsigned int)f2bf(vv[2]) | ((unsigned int)f2bf(vv[3]) << 16);
                    unsigned int* p = (unsigned int*)&Al[nl * ST + c4];
                    p[0] = lo; p[1] = hi;
                } else {
#pragma unroll
                    for (int e = 0; e < 4; ++e) {
                        const int c = c4 + e;
                        const int u = c / D;                 // const divisor
                        const int i = c - u * D;
                        Al[(i * TN + nl) * ST + u] = f2bf(vv[e]);
                    }
                }
            }
        }
    };

    f32x4 acc[MT][NT];
#pragma unroll
    for (int a = 0; a < MT; ++a)
#pragma unroll
        for (int b = 0; b < NT; ++b) acc[a][b] = (f32x4)0.0f;

    // ---- prologue: stage step 0
    stage_B(0, 0);
    stage_A(0, 0);
    __syncthreads();

    const int arow0  = wave_r * (MT * 16) + t16;
    const int nsub0  = wave_c * NT;

#pragma unroll 2
    for (int ks = 0; ks < NSTEP; ++ks) {
        const int cur = ks & 1, nxt = cur ^ 1;
        if (ks + 1 < NSTEP) stage_B(nxt, ks + 1);   // async DMA, in flight over MFMAs
        // frag reads from cur
        const unsigned short* __restrict__ Al = Alds + cur * A_BUF;
        const unsigned short* __restrict__ Bl = Blds + cur * B_BUF;
        bf16x8 afr[MT], bfr[NT];
#pragma unroll
        for (int tm = 0; tm < MT; ++tm)
            afr[tm] = *(const bf16x8*)&Al[(arow0 + tm * 16) * ST + q * 8];
#pragma unroll
        for (int tv = 0; tv < NT; ++tv)
            bfr[tv] = *(const bf16x8*)&Bl[(nsub0 + tv) * 512 + lane * 8];
        if (ks + 1 < NSTEP) stage_A(nxt, ks + 1);   // loads+convert+write, overlaps
#pragma unroll
        for (int tv = 0; tv < NT; ++tv)
#pragma unroll
            for (int tm = 0; tm < MT; ++tm)
                acc[tm][tv] = __builtin_amdgcn_mfma_f32_16x16x32_bf16(afr[tm], bfr[tv], acc[tm][tv], 0, 0, 0);
        __syncthreads();   // nxt buffers ready; all reads of cur done
    }

    // ---- epilogue: C/D layout col=lane&15, row=q*4+r
    const int vcol0 = nb * BN + wave_c * (NT * 16) + t16;
#pragma unroll
    for (int tm = 0; tm < MT; ++tm) {
#pragma unroll
        for (int tv = 0; tv < NT; ++tv) {
#pragma unroll
            for (int r = 0; r < 4; ++r) {
                const int lrow = wave_r * (MT * 16) + tm * 16 + q * 4 + r;
                const int i    = lrow / TN;          // TN pow2 -> shift
                const int nl   = lrow - i * TN;
                out[(n0 + nl) * ROWLEN + X_OFF + (vcol0 + tv * 16) * D + i] = acc[tm][tv][r] * scale;
            }
        }
    }
}

// 1536 wgs, interleaved b%3: 512 per segment
__global__ __launch_bounds__(512, 4) void fused_gemm(const float* __restrict__ x,
                                                     const unsigned short* __restrict__ wt,
                                                     float* __restrict__ out) {
    extern __shared__ unsigned short lds[];
    const int b = blockIdx.x;
    const int wid = b / 3;
    const int r = b - wid * 3;
    if (r == 0) {
        // seg0: M=16384, N=512 (2 n-blocks of 256), M_LOG=64, waves 1x8, MT=4 NT=2
        seg_body<512, 1, 64, 256, 0, 0, 1>(wid, x, wt, out, 0.044194173824f, lds);
    } else if (r == 1) {
        // seg1: M=49152, N=256, M_LOG=96, waves 2x4, MT=3 NT=4
        seg_body<256, 3, 32, 256, 512, 262144, 2>(wid, x, wt, out, 0.0625f, lds);
    } else {
        // seg2: M=81920, N=128, M_LOG=160, waves 2x4, MT=5 NT=2
        seg_body<128, 5, 32, 128, 1280, 327680, 2>(wid, x, wt, out, 0.088388347648f, lds);
    }
}

extern "C" void kernel_launch(void* const* d_in, const int* in_sizes, int n_in,
                              void* d_out, int out_size, void* d_ws, size_t ws_size,
                              hipStream_t stream) {
    const float* x = (const float*)d_in[0];
    const float* w = (const float*)d_in[1];
    float* out = (float*)d_out;
    unsigned short* wt = (unsigned short*)d_ws;   // 344064 bf16 = 688 KB, L2-resident

    hipLaunchKernelGGL(prep_weights, dim3(1344), dim3(256), 0, stream, w, wt);
    // dyn LDS = max over segs = seg1: (2*96*40 + 2*16*512)*2B = 48128 B
    hipLaunchKernelGGL(fused_gemm, dim3(1536), dim3(512), 48128, stream, x, wt, out);
}